// Round 1
// baseline (1036.158 us; speedup 1.0000x reference)
//
#include <hip/hip_runtime.h>

#define NN 100000
#define NE 1600000
#define DF 50
#define NC 47

__global__ void deg_kernel(const int* __restrict__ dst, unsigned int* __restrict__ deg, int E) {
    int e = blockIdx.x * blockDim.x + threadIdx.x;
    if (e < E) atomicAdd(&deg[dst[e]], 1u);
}

__global__ void dinv_kernel(const unsigned int* __restrict__ deg, float* __restrict__ dinv,
                            float* __restrict__ selfw, int N) {
    int n = blockIdx.x * blockDim.x + threadIdx.x;
    if (n < N) {
        float d = 1.0f + (float)deg[n];
        float r = rsqrtf(d);
        dinv[n] = r;
        selfw[n] = r * r;
    }
}

// h_new[n,:] = selfw[n] * h[n,:]  (writes every element; doubles as the zero-init)
__global__ void self_init_kernel(const float* __restrict__ h, const float* __restrict__ selfw,
                                 float* __restrict__ hn, int total) {
    int i = blockIdx.x * blockDim.x + threadIdx.x;
    if (i < total) {
        int n = i / DF;
        hn[i] = selfw[n] * h[i];
    }
}

// 32 lanes per edge; lane d handles feature d and d+32
__global__ void scatter_kernel(const float* __restrict__ h, const int* __restrict__ src,
                               const int* __restrict__ dst, const float* __restrict__ dinv,
                               float* __restrict__ hn, int E) {
    int t = blockIdx.x * blockDim.x + threadIdx.x;
    int e = t >> 5;
    int d = t & 31;
    if (e >= E) return;
    int s = src[e];
    int q = dst[e];
    float w = dinv[s] * dinv[q];
    const float* hs = h + (long)s * DF;
    float* hd = hn + (long)q * DF;
    unsafeAtomicAdd(&hd[d], w * hs[d]);
    int d2 = d + 32;
    if (d2 < DF) unsafeAtomicAdd(&hd[d2], w * hs[d2]);
}

// one wave per node; lanes 0..46 each compute one class
__global__ __launch_bounds__(256) void fc_kernel(const float* __restrict__ h,
                                                 const float* __restrict__ W,
                                                 const float* __restrict__ b,
                                                 float* __restrict__ out, int N) {
    __shared__ float Wt[DF][NC + 1];   // transposed: lane-contiguous, conflict-free
    __shared__ float bs[NC];
    for (int i = threadIdx.x; i < NC * DF; i += blockDim.x) {
        int c = i / DF, d = i % DF;
        Wt[d][c] = W[i];
    }
    if (threadIdx.x < NC) bs[threadIdx.x] = b[threadIdx.x];
    __syncthreads();
    int wave = (int)((blockIdx.x * blockDim.x + threadIdx.x) >> 6);
    int lane = threadIdx.x & 63;
    if (wave >= N) return;
    const float* hr = h + (long)wave * DF;
    if (lane < NC) {
        float acc = 0.f;
        #pragma unroll
        for (int d = 0; d < DF; ++d) acc += hr[d] * Wt[d][lane];
        out[(long)wave * NC + lane] = acc + bs[lane];
    }
}

extern "C" void kernel_launch(void* const* d_in, const int* in_sizes, int n_in,
                              void* d_out, int out_size, void* d_ws, size_t ws_size,
                              hipStream_t stream) {
    const float* feat = (const float*)d_in[0];
    const float* W    = (const float*)d_in[1];
    const float* b    = (const float*)d_in[2];
    const int*  esrc  = (const int*)d_in[3];
    const int*  edst  = (const int*)d_in[4];
    // d_in[5] is K — a Python scalar, always 2 for this problem; host loop below.
    float* out = (float*)d_out;

    char* ws = (char*)d_ws;
    unsigned int* deg = (unsigned int*)ws; ws += NN * sizeof(unsigned int);
    float* dinv  = (float*)ws; ws += NN * sizeof(float);
    float* selfw = (float*)ws; ws += NN * sizeof(float);
    float* h1 = (float*)ws; ws += (size_t)NN * DF * sizeof(float);
    float* h2 = (float*)ws;

    hipMemsetAsync(deg, 0, NN * sizeof(unsigned int), stream);

    deg_kernel<<<(NE + 255) / 256, 256, 0, stream>>>(edst, deg, NE);
    dinv_kernel<<<(NN + 255) / 256, 256, 0, stream>>>(deg, dinv, selfw, NN);

    const int total = NN * DF;
    // hop 1: feat -> h1
    self_init_kernel<<<(total + 255) / 256, 256, 0, stream>>>(feat, selfw, h1, total);
    scatter_kernel<<<((size_t)NE * 32 + 255) / 256, 256, 0, stream>>>(feat, esrc, edst, dinv, h1, NE);
    // hop 2: h1 -> h2
    self_init_kernel<<<(total + 255) / 256, 256, 0, stream>>>(h1, selfw, h2, total);
    scatter_kernel<<<((size_t)NE * 32 + 255) / 256, 256, 0, stream>>>(h1, esrc, edst, dinv, h2, NE);

    // FC: out = h2 @ W^T + b   (one wave per node)
    fc_kernel<<<(NN * 64 + 255) / 256, 256, 0, stream>>>(h2, W, b, out, NN);
}

// Round 2
// 545.513 us; speedup vs baseline: 1.8994x; 1.8994x over previous
//
#include <hip/hip_runtime.h>

#define NN 100000
#define NE 1600000
#define DF 50
#define NC 47

static_assert(NN % 4 == 0, "grid exactness for hop kernels");

__global__ void deg_kernel(const int* __restrict__ dst, unsigned* __restrict__ deg, int E) {
    int e = blockIdx.x * blockDim.x + threadIdx.x;
    if (e < E) atomicAdd(&deg[dst[e]], 1u);
}

// Per-node: dinv/selfw; CSR row allocation via wave scan + one atomic per wave.
// Row ranges are disjoint but in arbitrary order — grouping is all we need.
__global__ void alloc_kernel(const unsigned* __restrict__ deg, float* __restrict__ dinv,
                             float* __restrict__ selfw, unsigned* __restrict__ rowStart,
                             unsigned* __restrict__ total, int N) {
    int n = blockIdx.x * blockDim.x + threadIdx.x;
    int lane = threadIdx.x & 63;
    unsigned d = (n < N) ? deg[n] : 0u;
    unsigned s = d;                      // inclusive wave scan
    #pragma unroll
    for (int off = 1; off < 64; off <<= 1) {
        unsigned t = __shfl_up(s, off);
        if (lane >= off) s += t;
    }
    unsigned waveSum = __shfl(s, 63);
    unsigned base = 0;
    if (lane == 63) base = atomicAdd(total, waveSum);
    base = __shfl(base, 63);
    if (n < N) {
        rowStart[n] = base + s - d;      // exclusive position within wave
        float dd = 1.0f + (float)d;
        float r = rsqrtf(dd);
        dinv[n] = r;
        selfw[n] = r * r;
    }
}

__global__ void fill_kernel(const int* __restrict__ src, const int* __restrict__ dst,
                            const float* __restrict__ dinv, const unsigned* __restrict__ rowStart,
                            unsigned* __restrict__ cursor, int* __restrict__ col,
                            float* __restrict__ wgt, int E) {
    int e = blockIdx.x * blockDim.x + threadIdx.x;
    if (e >= E) return;
    int s = src[e], q = dst[e];
    unsigned pos = atomicAdd(&cursor[q], 1u);
    unsigned idx = rowStart[q] + pos;
    col[idx] = s;
    wgt[idx] = dinv[s] * dinv[q];
}

// One wave per dst node. Lanes preload up to 64 (col,wgt) pairs, broadcast via shfl,
// lanes 0..DF-1 gather h[src][lane] and FMA. FUSE=true applies FC through LDS.
template<bool FUSE>
__global__ __launch_bounds__(256) void hop_kernel(const float* __restrict__ h,
    const int* __restrict__ col, const float* __restrict__ wgt,
    const unsigned* __restrict__ rowStart, const unsigned* __restrict__ deg,
    const float* __restrict__ selfw, float* __restrict__ hn,
    const float* __restrict__ W, const float* __restrict__ b,
    float* __restrict__ out, int N) {

    __shared__ float sWt[FUSE ? DF : 1][NC + 1];
    __shared__ float sh[4][DF];
    __shared__ float sb[FUSE ? NC : 1];

    int lane = threadIdx.x & 63;
    int wib  = threadIdx.x >> 6;
    int wid  = (int)((blockIdx.x * blockDim.x + threadIdx.x) >> 6);

    if constexpr (FUSE) {
        for (int i = threadIdx.x; i < NC * DF; i += 256) {
            int c = i / DF, d = i % DF;
            sWt[d][c] = W[i];
        }
        if (threadIdx.x < NC) sb[threadIdx.x] = b[threadIdx.x];
        __syncthreads();
    }

    unsigned rs = rowStart[wid];
    unsigned d  = deg[wid];
    float acc = 0.f;
    for (unsigned j0 = 0; j0 < d; j0 += 64u) {
        int   ci = 0;
        float wi = 0.f;
        unsigned j = j0 + (unsigned)lane;
        if (j < d) { ci = col[rs + j]; wi = wgt[rs + j]; }
        int m = (int)min(64u, d - j0);
        for (int k = 0; k < m; ++k) {
            int   ck = __shfl(ci, k);
            float wk = __shfl(wi, k);
            if (lane < DF) acc += wk * h[(long)ck * DF + lane];
        }
    }
    if (lane < DF) acc += selfw[wid] * h[(long)wid * DF + lane];

    if constexpr (FUSE) {
        if (lane < DF) sh[wib][lane] = acc;
        __syncthreads();
        if (lane < NC) {
            float o = sb[lane];
            #pragma unroll
            for (int dd = 0; dd < DF; ++dd) o += sh[wib][dd] * sWt[dd][lane];
            out[(long)wid * NC + lane] = o;
        }
    } else {
        if (lane < DF) hn[(long)wid * DF + lane] = acc;
    }
}

extern "C" void kernel_launch(void* const* d_in, const int* in_sizes, int n_in,
                              void* d_out, int out_size, void* d_ws, size_t ws_size,
                              hipStream_t stream) {
    const float* feat = (const float*)d_in[0];
    const float* W    = (const float*)d_in[1];
    const float* b    = (const float*)d_in[2];
    const int*  esrc  = (const int*)d_in[3];
    const int*  edst  = (const int*)d_in[4];
    float* out = (float*)d_out;

    char* ws = (char*)d_ws;
    unsigned* deg      = (unsigned*)ws; ws += NN * sizeof(unsigned);
    unsigned* cursor   = (unsigned*)ws; ws += NN * sizeof(unsigned);
    unsigned* total    = (unsigned*)ws; ws += 4 * sizeof(unsigned);  // padded
    unsigned* rowStart = (unsigned*)ws; ws += NN * sizeof(unsigned);
    float*    dinv     = (float*)ws;    ws += NN * sizeof(float);
    float*    selfw    = (float*)ws;    ws += NN * sizeof(float);
    int*      col      = (int*)ws;      ws += (size_t)NE * sizeof(int);
    float*    wgt      = (float*)ws;    ws += (size_t)NE * sizeof(float);
    float*    h1       = (float*)ws;

    // zero deg + cursor + total in one shot (they are contiguous)
    hipMemsetAsync(deg, 0, (2 * NN + 4) * sizeof(unsigned), stream);

    deg_kernel<<<(NE + 255) / 256, 256, 0, stream>>>(edst, deg, NE);
    alloc_kernel<<<(NN + 255) / 256, 256, 0, stream>>>(deg, dinv, selfw, rowStart, total, NN);
    fill_kernel<<<(NE + 255) / 256, 256, 0, stream>>>(esrc, edst, dinv, rowStart, cursor, col, wgt, NE);

    const int hop_blocks = NN / 4;  // one wave per node, 4 waves/block, exact
    hop_kernel<false><<<hop_blocks, 256, 0, stream>>>(feat, col, wgt, rowStart, deg, selfw,
                                                      h1, nullptr, nullptr, nullptr, NN);
    hop_kernel<true><<<hop_blocks, 256, 0, stream>>>(h1, col, wgt, rowStart, deg, selfw,
                                                     nullptr, W, b, out, NN);
}

// Round 3
// 455.197 us; speedup vs baseline: 2.2763x; 1.1984x over previous
//
#include <hip/hip_runtime.h>

#define NN 100000
#define NE 1600000
#define DF 50
#define NC 47
#define DP 64   // padded feature dim (16 float4 per row, 256B line-aligned)

static_assert(NN % 4 == 0, "grid exactness for hop kernels");

__global__ void deg_kernel(const int* __restrict__ dst, unsigned* __restrict__ deg, int E) {
    int e = blockIdx.x * blockDim.x + threadIdx.x;
    if (e < E) atomicAdd(&deg[dst[e]], 1u);
}

// Per-node: dinv/selfw; CSR row allocation via wave scan + one atomic per wave.
__global__ void alloc_kernel(const unsigned* __restrict__ deg, float* __restrict__ dinv,
                             float* __restrict__ selfw, unsigned* __restrict__ rowStart,
                             unsigned* __restrict__ total, int N) {
    int n = blockIdx.x * blockDim.x + threadIdx.x;
    int lane = threadIdx.x & 63;
    unsigned d = (n < N) ? deg[n] : 0u;
    unsigned s = d;
    #pragma unroll
    for (int off = 1; off < 64; off <<= 1) {
        unsigned t = __shfl_up(s, off);
        if (lane >= off) s += t;
    }
    unsigned waveSum = __shfl(s, 63);
    unsigned base = 0;
    if (lane == 63) base = atomicAdd(total, waveSum);
    base = __shfl(base, 63);
    if (n < N) {
        rowStart[n] = base + s - d;
        float dd = 1.0f + (float)d;
        float r = rsqrtf(dd);
        dinv[n] = r;
        selfw[n] = r * r;
    }
}

// col only — weights are recomputed from dinv in the hop (dst factor folded out).
__global__ void fill_kernel(const int* __restrict__ src, const int* __restrict__ dst,
                            const unsigned* __restrict__ rowStart,
                            unsigned* __restrict__ cursor, int* __restrict__ col, int E) {
    int e = blockIdx.x * blockDim.x + threadIdx.x;
    if (e >= E) return;
    int s = src[e], q = dst[e];
    unsigned pos = atomicAdd(&cursor[q], 1u);
    col[rowStart[q] + pos] = s;
}

// feat [NN,50] -> featp [NN,64] zero-padded
__global__ void pad_kernel(const float* __restrict__ f, float* __restrict__ fp, int total) {
    int i = blockIdx.x * blockDim.x + threadIdx.x;
    if (i < total) {
        int n = i >> 6, l = i & 63;
        fp[i] = (l < DF) ? f[n * DF + l] : 0.f;
    }
}

// One wave per dst node, padded float4 rows. 16 edges per iteration, 4 rows per
// dwordx4 gather, 4 loads in flight. FUSE=true applies the FC epilogue via LDS.
template<bool FUSE>
__global__ __launch_bounds__(256) void hop_kernel(const float4* __restrict__ h4,
    const int* __restrict__ col, const unsigned* __restrict__ rowStart,
    const unsigned* __restrict__ deg, const float* __restrict__ dinv,
    const float* __restrict__ selfw, float4* __restrict__ hn4,
    const float* __restrict__ W, const float* __restrict__ b,
    float* __restrict__ out) {

    __shared__ float  sWt[FUSE ? DF : 1][NC + 1];
    __shared__ float4 sh4[4][16];
    __shared__ float  sb[FUSE ? NC : 1];

    int lane = threadIdx.x & 63;
    int wib  = threadIdx.x >> 6;
    int wid  = (int)((blockIdx.x * blockDim.x + threadIdx.x) >> 6);
    int grp  = lane >> 4;    // edge sub-group 0..3
    int qid  = lane & 15;    // float4 index within row

    if constexpr (FUSE) {
        for (int i = threadIdx.x; i < NC * DF; i += 256) {
            int c = i / DF, d = i % DF;
            sWt[d][c] = W[i];
        }
        if (threadIdx.x < NC) sb[threadIdx.x] = b[threadIdx.x];
        __syncthreads();
    }

    unsigned rs = rowStart[wid];
    unsigned d  = deg[wid];
    float4 acc = make_float4(0.f, 0.f, 0.f, 0.f);

    for (unsigned j0 = 0; j0 < d; j0 += 64u) {
        int   ci = 0;
        float wi = 0.f;
        unsigned j = j0 + (unsigned)lane;
        if (j < d) { ci = col[rs + j]; wi = dinv[ci]; }   // src factor only
        int m = (int)min(64u, d - j0);
        for (int k = 0; k < m; k += 16) {
            // kk = k + 4*sub + grp <= 48 + 12 + 3 = 63: no wrap, tail weights are 0
            int kk0 = k + grp, kk1 = kk0 + 4, kk2 = kk0 + 8, kk3 = kk0 + 12;
            int   c0 = __shfl(ci, kk0); float w0 = __shfl(wi, kk0);
            int   c1 = __shfl(ci, kk1); float w1 = __shfl(wi, kk1);
            int   c2 = __shfl(ci, kk2); float w2 = __shfl(wi, kk2);
            int   c3 = __shfl(ci, kk3); float w3 = __shfl(wi, kk3);
            float4 v0 = h4[(long)c0 * 16 + qid];
            float4 v1 = h4[(long)c1 * 16 + qid];
            float4 v2 = h4[(long)c2 * 16 + qid];
            float4 v3 = h4[(long)c3 * 16 + qid];
            acc.x += w0 * v0.x + w1 * v1.x + w2 * v2.x + w3 * v3.x;
            acc.y += w0 * v0.y + w1 * v1.y + w2 * v2.y + w3 * v3.y;
            acc.z += w0 * v0.z + w1 * v1.z + w2 * v2.z + w3 * v3.z;
            acc.w += w0 * v0.w + w1 * v1.w + w2 * v2.w + w3 * v3.w;
        }
    }

    // combine the 4 edge sub-groups (lanes sharing qid)
    acc.x += __shfl_xor(acc.x, 16); acc.x += __shfl_xor(acc.x, 32);
    acc.y += __shfl_xor(acc.y, 16); acc.y += __shfl_xor(acc.y, 32);
    acc.z += __shfl_xor(acc.z, 16); acc.z += __shfl_xor(acc.z, 32);
    acc.w += __shfl_xor(acc.w, 16); acc.w += __shfl_xor(acc.w, 32);

    // row scale (dst factor) + self loop
    float  dw = dinv[wid];
    float  sw = selfw[wid];
    float4 hv = h4[(long)wid * 16 + qid];
    float4 r;
    r.x = dw * acc.x + sw * hv.x;
    r.y = dw * acc.y + sw * hv.y;
    r.z = dw * acc.z + sw * hv.z;
    r.w = dw * acc.w + sw * hv.w;

    if constexpr (FUSE) {
        if (grp == 0) sh4[wib][qid] = r;
        __syncthreads();
        if (lane < NC) {
            const float* hr = (const float*)sh4[wib];
            float o = sb[lane];
            #pragma unroll
            for (int dd = 0; dd < DF; ++dd) o += hr[dd] * sWt[dd][lane];
            out[(long)wid * NC + lane] = o;
        }
    } else {
        if (grp == 0) hn4[(long)wid * 16 + qid] = r;
    }
}

extern "C" void kernel_launch(void* const* d_in, const int* in_sizes, int n_in,
                              void* d_out, int out_size, void* d_ws, size_t ws_size,
                              hipStream_t stream) {
    const float* feat = (const float*)d_in[0];
    const float* W    = (const float*)d_in[1];
    const float* b    = (const float*)d_in[2];
    const int*  esrc  = (const int*)d_in[3];
    const int*  edst  = (const int*)d_in[4];
    float* out = (float*)d_out;

    char* ws = (char*)d_ws;
    unsigned* deg      = (unsigned*)ws; ws += NN * sizeof(unsigned);
    unsigned* cursor   = (unsigned*)ws; ws += NN * sizeof(unsigned);
    unsigned* total    = (unsigned*)ws; ws += 4 * sizeof(unsigned);
    unsigned* rowStart = (unsigned*)ws; ws += NN * sizeof(unsigned);
    float*    dinv     = (float*)ws;    ws += NN * sizeof(float);
    float*    selfw    = (float*)ws;    ws += NN * sizeof(float);
    int*      col      = (int*)ws;      ws += (size_t)NE * sizeof(int);
    float*    featp    = (float*)ws;    ws += (size_t)NN * DP * sizeof(float);
    float*    h1p      = (float*)ws;

    hipMemsetAsync(deg, 0, (2 * NN + 4) * sizeof(unsigned), stream);

    deg_kernel<<<(NE + 255) / 256, 256, 0, stream>>>(edst, deg, NE);
    alloc_kernel<<<(NN + 255) / 256, 256, 0, stream>>>(deg, dinv, selfw, rowStart, total, NN);
    fill_kernel<<<(NE + 255) / 256, 256, 0, stream>>>(esrc, edst, rowStart, cursor, col, NE);
    pad_kernel<<<(NN * DP + 255) / 256, 256, 0, stream>>>(feat, featp, NN * DP);

    const int hop_blocks = NN / 4;  // one wave per node, exact
    hop_kernel<false><<<hop_blocks, 256, 0, stream>>>((const float4*)featp, col, rowStart, deg,
                                                      dinv, selfw, (float4*)h1p,
                                                      nullptr, nullptr, nullptr);
    hop_kernel<true><<<hop_blocks, 256, 0, stream>>>((const float4*)h1p, col, rowStart, deg,
                                                     dinv, selfw, nullptr,
                                                     W, b, out);
}

// Round 4
// 439.544 us; speedup vs baseline: 2.3573x; 1.0356x over previous
//
#include <hip/hip_runtime.h>
#include <hip/hip_fp16.h>

#define NN 100000
#define NE 1600000
#define DF 50
#define NC 47
#define DP 64   // padded feature dim; fp16 row = 128 B = 8 x 16B chunks

static_assert(NN % 4 == 0, "grid exactness for hop kernels");
static_assert(NE % 4 == 0, "int4 edge loads");

__global__ void deg_kernel(const int4* __restrict__ dst4, unsigned* __restrict__ deg, int E4) {
    int t = blockIdx.x * blockDim.x + threadIdx.x;
    if (t < E4) {
        int4 q = dst4[t];
        atomicAdd(&deg[q.x], 1u);
        atomicAdd(&deg[q.y], 1u);
        atomicAdd(&deg[q.z], 1u);
        atomicAdd(&deg[q.w], 1u);
    }
}

// Per-node: dinv/selfw; CSR row allocation via wave scan + one atomic per wave.
__global__ void alloc_kernel(const unsigned* __restrict__ deg, float* __restrict__ dinv,
                             float* __restrict__ selfw, unsigned* __restrict__ rowStart,
                             unsigned* __restrict__ total, int N) {
    int n = blockIdx.x * blockDim.x + threadIdx.x;
    int lane = threadIdx.x & 63;
    unsigned d = (n < N) ? deg[n] : 0u;
    unsigned s = d;
    #pragma unroll
    for (int off = 1; off < 64; off <<= 1) {
        unsigned t = __shfl_up(s, off);
        if (lane >= off) s += t;
    }
    unsigned waveSum = __shfl(s, 63);
    unsigned base = 0;
    if (lane == 63) base = atomicAdd(total, waveSum);
    base = __shfl(base, 63);
    if (n < N) {
        rowStart[n] = base + s - d;
        float dd = 1.0f + (float)d;
        float r = rsqrtf(dd);
        dinv[n] = r;
        selfw[n] = r * r;
    }
}

__global__ void fill_kernel(const int4* __restrict__ src4, const int4* __restrict__ dst4,
                            const unsigned* __restrict__ rowStart,
                            unsigned* __restrict__ cursor, int* __restrict__ col, int E4) {
    int t = blockIdx.x * blockDim.x + threadIdx.x;
    if (t >= E4) return;
    int4 s = src4[t];
    int4 q = dst4[t];
    unsigned p;
    p = atomicAdd(&cursor[q.x], 1u); col[rowStart[q.x] + p] = s.x;
    p = atomicAdd(&cursor[q.y], 1u); col[rowStart[q.y] + p] = s.y;
    p = atomicAdd(&cursor[q.z], 1u); col[rowStart[q.z] + p] = s.z;
    p = atomicAdd(&cursor[q.w], 1u); col[rowStart[q.w] + p] = s.w;
}

// feat [NN,50] fp32 -> featp [NN,64] fp16 zero-padded
__global__ void pad_kernel(const float* __restrict__ f, __half* __restrict__ fp, int total) {
    int i = blockIdx.x * blockDim.x + threadIdx.x;
    if (i < total) {
        int n = i >> 6, l = i & 63;
        fp[i] = __float2half((l < DF) ? f[n * DF + l] : 0.f);
    }
}

__device__ inline void fma8(float* acc, float4 v, float w) {
    const __half2* p = (const __half2*)&v;
    #pragma unroll
    for (int i = 0; i < 4; ++i) {
        float2 f = __half22float2(p[i]);
        acc[2 * i]     += w * f.x;
        acc[2 * i + 1] += w * f.y;
    }
}

// One wave per dst node, fp16 rows of 128B. 8 lanes per row (8x16B chunks),
// 8 edge-groups, 4 gathers in flight, 32 edges per inner iteration.
template<bool FUSE>
__global__ __launch_bounds__(256) void hop_kernel(const float4* __restrict__ h4,
    const int* __restrict__ col, const unsigned* __restrict__ rowStart,
    const unsigned* __restrict__ deg, const float* __restrict__ dinv,
    const float* __restrict__ selfw, float4* __restrict__ hn4,
    const float* __restrict__ W, const float* __restrict__ b,
    float* __restrict__ out) {

    __shared__ float sWt[FUSE ? DF : 1][NC + 1];
    __shared__ float sh[4][DP];
    __shared__ float sb[FUSE ? NC : 1];

    int lane = threadIdx.x & 63;
    int wib  = threadIdx.x >> 6;
    int wid  = (int)((blockIdx.x * blockDim.x + threadIdx.x) >> 6);
    int grp  = lane >> 3;   // edge sub-group 0..7
    int qid  = lane & 7;    // 16B chunk within the 128B row

    if constexpr (FUSE) {
        for (int i = threadIdx.x; i < NC * DF; i += 256) {
            int c = i / DF, d = i % DF;
            sWt[d][c] = W[i];
        }
        if (threadIdx.x < NC) sb[threadIdx.x] = b[threadIdx.x];
        __syncthreads();
    }

    unsigned rs = rowStart[wid];
    unsigned d  = deg[wid];
    float acc[8] = {0.f, 0.f, 0.f, 0.f, 0.f, 0.f, 0.f, 0.f};

    for (unsigned j0 = 0; j0 < d; j0 += 64u) {
        int   ci = 0;
        float wi = 0.f;
        unsigned j = j0 + (unsigned)lane;
        if (j < d) { ci = col[rs + j]; wi = dinv[ci]; }   // src factor only
        int m = (int)min(64u, d - j0);
        for (int k = 0; k < m; k += 32) {
            // kk = k + 8s + grp <= 32 + 24 + 7 = 63: no wrap; tail weights are 0
            int kk = k + grp;
            int   c0 = __shfl(ci, kk);      float w0 = __shfl(wi, kk);
            int   c1 = __shfl(ci, kk + 8);  float w1 = __shfl(wi, kk + 8);
            int   c2 = __shfl(ci, kk + 16); float w2 = __shfl(wi, kk + 16);
            int   c3 = __shfl(ci, kk + 24); float w3 = __shfl(wi, kk + 24);
            float4 v0 = h4[(long)c0 * 8 + qid];
            float4 v1 = h4[(long)c1 * 8 + qid];
            float4 v2 = h4[(long)c2 * 8 + qid];
            float4 v3 = h4[(long)c3 * 8 + qid];
            fma8(acc, v0, w0);
            fma8(acc, v1, w1);
            fma8(acc, v2, w2);
            fma8(acc, v3, w3);
        }
    }

    // combine the 8 edge sub-groups (lanes sharing qid)
    #pragma unroll
    for (int i = 0; i < 8; ++i) {
        acc[i] += __shfl_xor(acc[i], 8);
        acc[i] += __shfl_xor(acc[i], 16);
        acc[i] += __shfl_xor(acc[i], 32);
    }

    // row scale (dst factor) + self loop
    float  dw = dinv[wid];
    float  sw = selfw[wid];
    float4 hv = h4[(long)wid * 8 + qid];
    const __half2* hp = (const __half2*)&hv;
    float r[8];
    #pragma unroll
    for (int i = 0; i < 4; ++i) {
        float2 f = __half22float2(hp[i]);
        r[2 * i]     = dw * acc[2 * i]     + sw * f.x;
        r[2 * i + 1] = dw * acc[2 * i + 1] + sw * f.y;
    }

    if constexpr (FUSE) {
        if (grp == 0) {
            #pragma unroll
            for (int i = 0; i < 8; ++i) sh[wib][qid * 8 + i] = r[i];
        }
        __syncthreads();
        if (lane < NC) {
            float o = sb[lane];
            #pragma unroll
            for (int dd = 0; dd < DF; ++dd) o += sh[wib][dd] * sWt[dd][lane];
            out[(long)wid * NC + lane] = o;
        }
    } else {
        if (grp == 0) {
            float4 ov;
            __half2* op = (__half2*)&ov;
            #pragma unroll
            for (int i = 0; i < 4; ++i) op[i] = __floats2half2_rn(r[2 * i], r[2 * i + 1]);
            hn4[(long)wid * 8 + qid] = ov;
        }
    }
}

extern "C" void kernel_launch(void* const* d_in, const int* in_sizes, int n_in,
                              void* d_out, int out_size, void* d_ws, size_t ws_size,
                              hipStream_t stream) {
    const float* feat = (const float*)d_in[0];
    const float* W    = (const float*)d_in[1];
    const float* b    = (const float*)d_in[2];
    const int*  esrc  = (const int*)d_in[3];
    const int*  edst  = (const int*)d_in[4];
    float* out = (float*)d_out;

    char* ws = (char*)d_ws;
    unsigned* deg      = (unsigned*)ws; ws += NN * sizeof(unsigned);
    unsigned* cursor   = (unsigned*)ws; ws += NN * sizeof(unsigned);
    unsigned* total    = (unsigned*)ws; ws += 4 * sizeof(unsigned);
    unsigned* rowStart = (unsigned*)ws; ws += NN * sizeof(unsigned);
    float*    dinv     = (float*)ws;    ws += NN * sizeof(float);
    float*    selfw    = (float*)ws;    ws += NN * sizeof(float);
    int*      col      = (int*)ws;      ws += (size_t)NE * sizeof(int);
    __half*   featp    = (__half*)ws;   ws += (size_t)NN * DP * sizeof(__half);
    __half*   h1p      = (__half*)ws;

    hipMemsetAsync(deg, 0, (2 * NN + 4) * sizeof(unsigned), stream);

    deg_kernel<<<(NE / 4 + 255) / 256, 256, 0, stream>>>((const int4*)edst, deg, NE / 4);
    alloc_kernel<<<(NN + 255) / 256, 256, 0, stream>>>(deg, dinv, selfw, rowStart, total, NN);
    fill_kernel<<<(NE / 4 + 255) / 256, 256, 0, stream>>>((const int4*)esrc, (const int4*)edst,
                                                          rowStart, cursor, col, NE / 4);
    pad_kernel<<<(NN * DP + 255) / 256, 256, 0, stream>>>(feat, featp, NN * DP);

    const int hop_blocks = NN / 4;  // one wave per node, exact
    hop_kernel<false><<<hop_blocks, 256, 0, stream>>>((const float4*)featp, col, rowStart, deg,
                                                      dinv, selfw, (float4*)h1p,
                                                      nullptr, nullptr, nullptr);
    hop_kernel<true><<<hop_blocks, 256, 0, stream>>>((const float4*)h1p, col, rowStart, deg,
                                                     dinv, selfw, nullptr,
                                                     W, b, out);
}

// Round 5
// 413.112 us; speedup vs baseline: 2.5082x; 1.0640x over previous
//
#include <hip/hip_runtime.h>
#include <hip/hip_fp16.h>

#define NN 100000
#define NE 1600000
#define DF 50
#define NC 47
#define DP 64   // padded feature dim; fp16 row = 128 B = 8 x 16B chunks

static_assert(NN % 8 == 0, "grid exactness for hop kernels");
static_assert(NE % 4 == 0, "int4 edge loads");

struct __align__(8) Edge { int c; float w; };   // col + dinv[src]

__global__ void deg_kernel(const int4* __restrict__ dst4, unsigned* __restrict__ deg, int E4) {
    int t = blockIdx.x * blockDim.x + threadIdx.x;
    if (t < E4) {
        int4 q = dst4[t];
        atomicAdd(&deg[q.x], 1u);
        atomicAdd(&deg[q.y], 1u);
        atomicAdd(&deg[q.z], 1u);
        atomicAdd(&deg[q.w], 1u);
    }
}

// Per-node: dinv/selfw; CSR row allocation via wave scan + one atomic per wave.
// Writes BOTH rowStart (for hops) and cursor (mutable fill cursor).
__global__ void alloc_kernel(const unsigned* __restrict__ deg, float* __restrict__ dinv,
                             float* __restrict__ selfw, unsigned* __restrict__ rowStart,
                             unsigned* __restrict__ cursor, unsigned* __restrict__ total, int N) {
    int n = blockIdx.x * blockDim.x + threadIdx.x;
    int lane = threadIdx.x & 63;
    unsigned d = (n < N) ? deg[n] : 0u;
    unsigned s = d;
    #pragma unroll
    for (int off = 1; off < 64; off <<= 1) {
        unsigned t = __shfl_up(s, off);
        if (lane >= off) s += t;
    }
    unsigned waveSum = __shfl(s, 63);
    unsigned base = 0;
    if (lane == 63) base = atomicAdd(total, waveSum);
    base = __shfl(base, 63);
    if (n < N) {
        unsigned rs = base + s - d;
        rowStart[n] = rs;
        cursor[n]   = rs;
        float dd = 1.0f + (float)d;
        float r = rsqrtf(dd);
        dinv[n] = r;
        selfw[n] = r * r;
    }
}

// cursor[] pre-initialized to rowStart: atomicAdd yields the slot directly.
__global__ void fill_kernel(const int4* __restrict__ src4, const int4* __restrict__ dst4,
                            const float* __restrict__ dinv,
                            unsigned* __restrict__ cursor, Edge* __restrict__ ecw, int E4) {
    int t = blockIdx.x * blockDim.x + threadIdx.x;
    if (t >= E4) return;
    int4 s = src4[t];
    int4 q = dst4[t];
    unsigned p;
    p = atomicAdd(&cursor[q.x], 1u); ecw[p] = {s.x, dinv[s.x]};
    p = atomicAdd(&cursor[q.y], 1u); ecw[p] = {s.y, dinv[s.y]};
    p = atomicAdd(&cursor[q.z], 1u); ecw[p] = {s.z, dinv[s.z]};
    p = atomicAdd(&cursor[q.w], 1u); ecw[p] = {s.w, dinv[s.w]};
}

// feat [NN,50] fp32 -> featp [NN,64] fp16, one 16B chunk per thread
__global__ void pad_kernel(const float* __restrict__ f, float4* __restrict__ fp, int total8) {
    int t = blockIdx.x * blockDim.x + threadIdx.x;
    if (t >= total8) return;
    int n = t >> 3, c = t & 7;
    float v[8];
    #pragma unroll
    for (int i = 0; i < 8; ++i) {
        int e = c * 8 + i;
        v[i] = (e < DF) ? f[n * DF + e] : 0.f;
    }
    float4 ov;
    __half2* op = (__half2*)&ov;
    #pragma unroll
    for (int i = 0; i < 4; ++i) op[i] = __floats2half2_rn(v[2 * i], v[2 * i + 1]);
    fp[t] = ov;
}

__device__ inline void fma8(float* acc, float4 v, float w) {
    const __half2* p = (const __half2*)&v;
    #pragma unroll
    for (int i = 0; i < 4; ++i) {
        float2 f = __half22float2(p[i]);
        acc[2 * i]     += w * f.x;
        acc[2 * i + 1] += w * f.y;
    }
}

// One wave per TWO dst nodes: half-wave 0 -> node 2w, half-wave 1 -> node 2w+1.
// fp16 rows of 128B, 8 lanes per row, 4 gathers in flight (16 edges/node/body).
template<bool FUSE>
__global__ __launch_bounds__(256) void hop_kernel(const float4* __restrict__ h4,
    const Edge* __restrict__ ecw, const unsigned* __restrict__ rowStart,
    const unsigned* __restrict__ deg, const float* __restrict__ dinv,
    const float* __restrict__ selfw, float4* __restrict__ hn4,
    const float* __restrict__ W, const float* __restrict__ b,
    float* __restrict__ out) {

    __shared__ float sWt[FUSE ? DF : 1][NC + 1];
    __shared__ float sh[4][2][DP];
    __shared__ float sb[FUSE ? NC : 1];

    int lane = threadIdx.x & 63;
    int wib  = threadIdx.x >> 6;
    int wid  = (int)((blockIdx.x * blockDim.x + threadIdx.x) >> 6);
    int half = lane >> 5;          // which node this lane serves
    int l32  = lane & 31;
    int grp  = lane >> 3;          // 0..7 (row group per gather instr)
    int qid  = lane & 7;           // 16B chunk within the 128B row

    if constexpr (FUSE) {
        for (int i = threadIdx.x; i < NC * DF; i += 256) {
            int c = i / DF, d = i % DF;
            sWt[d][c] = W[i];
        }
        if (threadIdx.x < NC) sb[threadIdx.x] = b[threadIdx.x];
        __syncthreads();
    }

    int nd = 2 * wid + half;       // this lane's node
    unsigned rs = rowStart[nd];
    unsigned d  = deg[nd];
    unsigned dA = __shfl(d, 0);
    unsigned dB = __shfl(d, 32);
    unsigned dmax = max(dA, dB);

    float acc[8] = {0.f, 0.f, 0.f, 0.f, 0.f, 0.f, 0.f, 0.f};

    for (unsigned j0 = 0; j0 < dmax; j0 += 32u) {
        int   ci = 0;
        float wi = 0.f;
        unsigned j = j0 + (unsigned)l32;
        if (j < d) { Edge e = ecw[rs + j]; ci = e.c; wi = e.w; }
        unsigned m = min(32u, dmax - j0);
        for (unsigned k = 0; k < m; k += 16u) {
            // source lane for this lane's node, edge (k + 4*j2 + grp&3)
            int base = half * 32 + (int)k + (grp & 3);
            int s0 = base, s1 = base + 4, s2 = base + 8, s3 = base + 12;
            int   c0 = __shfl(ci, s0); float w0 = __shfl(wi, s0);
            int   c1 = __shfl(ci, s1); float w1 = __shfl(wi, s1);
            int   c2 = __shfl(ci, s2); float w2 = __shfl(wi, s2);
            int   c3 = __shfl(ci, s3); float w3 = __shfl(wi, s3);
            float4 v0 = h4[(long)c0 * 8 + qid];
            float4 v1 = h4[(long)c1 * 8 + qid];
            float4 v2 = h4[(long)c2 * 8 + qid];
            float4 v3 = h4[(long)c3 * 8 + qid];
            fma8(acc, v0, w0);
            fma8(acc, v1, w1);
            fma8(acc, v2, w2);
            fma8(acc, v3, w3);
        }
    }

    // combine the 4 row-groups within each half (lanes sharing qid)
    #pragma unroll
    for (int i = 0; i < 8; ++i) {
        acc[i] += __shfl_xor(acc[i], 8);
        acc[i] += __shfl_xor(acc[i], 16);
    }

    // row scale (dst factor) + self loop
    float  dw = dinv[nd];
    float  sw = selfw[nd];
    float4 hv = h4[(long)nd * 8 + qid];
    const __half2* hp = (const __half2*)&hv;
    float r[8];
    #pragma unroll
    for (int i = 0; i < 4; ++i) {
        float2 f = __half22float2(hp[i]);
        r[2 * i]     = dw * acc[2 * i]     + sw * f.x;
        r[2 * i + 1] = dw * acc[2 * i + 1] + sw * f.y;
    }

    if constexpr (FUSE) {
        if ((lane & 24) == 0) {
            #pragma unroll
            for (int i = 0; i < 8; ++i) sh[wib][half][qid * 8 + i] = r[i];
        }
        __syncthreads();
        #pragma unroll
        for (int n = 0; n < 2; ++n) {
            if (lane < NC) {
                float o = sb[lane];
                #pragma unroll
                for (int dd = 0; dd < DF; ++dd) o += sh[wib][n][dd] * sWt[dd][lane];
                out[(long)(2 * wid + n) * NC + lane] = o;
            }
        }
    } else {
        if ((lane & 24) == 0) {
            float4 ov;
            __half2* op = (__half2*)&ov;
            #pragma unroll
            for (int i = 0; i < 4; ++i) op[i] = __floats2half2_rn(r[2 * i], r[2 * i + 1]);
            hn4[(long)nd * 8 + qid] = ov;
        }
    }
}

extern "C" void kernel_launch(void* const* d_in, const int* in_sizes, int n_in,
                              void* d_out, int out_size, void* d_ws, size_t ws_size,
                              hipStream_t stream) {
    const float* feat = (const float*)d_in[0];
    const float* W    = (const float*)d_in[1];
    const float* b    = (const float*)d_in[2];
    const int*  esrc  = (const int*)d_in[3];
    const int*  edst  = (const int*)d_in[4];
    float* out = (float*)d_out;

    char* ws = (char*)d_ws;
    unsigned* deg      = (unsigned*)ws; ws += NN * sizeof(unsigned);
    unsigned* total    = (unsigned*)ws; ws += 4 * sizeof(unsigned);   // memset with deg
    unsigned* cursor   = (unsigned*)ws; ws += NN * sizeof(unsigned);
    unsigned* rowStart = (unsigned*)ws; ws += NN * sizeof(unsigned);
    float*    dinv     = (float*)ws;    ws += NN * sizeof(float);
    float*    selfw    = (float*)ws;    ws += NN * sizeof(float);
    Edge*     ecw      = (Edge*)ws;     ws += (size_t)NE * sizeof(Edge);
    __half*   featp    = (__half*)ws;   ws += (size_t)NN * DP * sizeof(__half);
    __half*   h1p      = (__half*)ws;

    hipMemsetAsync(deg, 0, NN * sizeof(unsigned) + 4 * sizeof(unsigned), stream);

    deg_kernel<<<(NE / 4 + 255) / 256, 256, 0, stream>>>((const int4*)edst, deg, NE / 4);
    alloc_kernel<<<(NN + 255) / 256, 256, 0, stream>>>(deg, dinv, selfw, rowStart, cursor, total, NN);
    fill_kernel<<<(NE / 4 + 255) / 256, 256, 0, stream>>>((const int4*)esrc, (const int4*)edst,
                                                          dinv, cursor, ecw, NE / 4);
    pad_kernel<<<(NN * 8 + 255) / 256, 256, 0, stream>>>(feat, (float4*)featp, NN * 8);

    const int hop_blocks = NN / 8;   // 2 nodes/wave, 4 waves/block, exact
    hop_kernel<false><<<hop_blocks, 256, 0, stream>>>((const float4*)featp, ecw, rowStart, deg,
                                                      dinv, selfw, (float4*)h1p,
                                                      nullptr, nullptr, nullptr);
    hop_kernel<true><<<hop_blocks, 256, 0, stream>>>((const float4*)h1p, ecw, rowStart, deg,
                                                     dinv, selfw, nullptr,
                                                     W, b, out);
}

// Round 6
// 385.295 us; speedup vs baseline: 2.6893x; 1.0722x over previous
//
#include <hip/hip_runtime.h>
#include <hip/hip_fp16.h>

#define NN 100000
#define NE 1600000
#define DF 50
#define NC 47
#define DP 64   // padded feature dim; fp16 row = 128 B = 8 x 16B chunks

static_assert(NN % 16 == 0, "grid exactness");
static_assert(NE % 8 == 0, "int4 x2 edge loads");

typedef _Float16 half8 __attribute__((ext_vector_type(8)));
typedef float float4v __attribute__((ext_vector_type(4)));

struct __align__(8) Edge { int c; float w; };   // col + dinv[src]

__global__ void deg_kernel(const int4* __restrict__ dst4, unsigned* __restrict__ deg, int E4) {
    int t = blockIdx.x * blockDim.x + threadIdx.x;
    if (t < E4) {
        int4 q = dst4[t];
        atomicAdd(&deg[q.x], 1u);
        atomicAdd(&deg[q.y], 1u);
        atomicAdd(&deg[q.z], 1u);
        atomicAdd(&deg[q.w], 1u);
    }
}

// Per-node: dinv/selfw; CSR row allocation via wave scan + one atomic per wave.
__global__ void alloc_kernel(const unsigned* __restrict__ deg, float* __restrict__ dinv,
                             float* __restrict__ selfw, unsigned* __restrict__ rowStart,
                             unsigned* __restrict__ cursor, unsigned* __restrict__ total, int N) {
    int n = blockIdx.x * blockDim.x + threadIdx.x;
    int lane = threadIdx.x & 63;
    unsigned d = (n < N) ? deg[n] : 0u;
    unsigned s = d;
    #pragma unroll
    for (int off = 1; off < 64; off <<= 1) {
        unsigned t = __shfl_up(s, off);
        if (lane >= off) s += t;
    }
    unsigned waveSum = __shfl(s, 63);
    unsigned base = 0;
    if (lane == 63) base = atomicAdd(total, waveSum);
    base = __shfl(base, 63);
    if (n < N) {
        unsigned rs = base + s - d;
        rowStart[n] = rs;
        cursor[n]   = rs;
        float dd = 1.0f + (float)d;
        float r = rsqrtf(dd);
        dinv[n] = r;
        selfw[n] = r * r;
    }
}

// 8 edges/thread: 8 outstanding slot-atomics before the dependent scattered stores.
__global__ void fill_kernel(const int4* __restrict__ src4, const int4* __restrict__ dst4,
                            const float* __restrict__ dinv,
                            unsigned* __restrict__ cursor, Edge* __restrict__ ecw, int E8) {
    int t = blockIdx.x * blockDim.x + threadIdx.x;
    if (t >= E8) return;
    int4 s0 = src4[2 * t],     q0 = dst4[2 * t];
    int4 s1 = src4[2 * t + 1], q1 = dst4[2 * t + 1];
    unsigned p0 = atomicAdd(&cursor[q0.x], 1u);
    unsigned p1 = atomicAdd(&cursor[q0.y], 1u);
    unsigned p2 = atomicAdd(&cursor[q0.z], 1u);
    unsigned p3 = atomicAdd(&cursor[q0.w], 1u);
    unsigned p4 = atomicAdd(&cursor[q1.x], 1u);
    unsigned p5 = atomicAdd(&cursor[q1.y], 1u);
    unsigned p6 = atomicAdd(&cursor[q1.z], 1u);
    unsigned p7 = atomicAdd(&cursor[q1.w], 1u);
    ecw[p0] = {s0.x, dinv[s0.x]};
    ecw[p1] = {s0.y, dinv[s0.y]};
    ecw[p2] = {s0.z, dinv[s0.z]};
    ecw[p3] = {s0.w, dinv[s0.w]};
    ecw[p4] = {s1.x, dinv[s1.x]};
    ecw[p5] = {s1.y, dinv[s1.y]};
    ecw[p6] = {s1.z, dinv[s1.z]};
    ecw[p7] = {s1.w, dinv[s1.w]};
}

// feat [NN,50] fp32 -> featp [NN,64] fp16, one 16B chunk per thread
__global__ void pad_kernel(const float* __restrict__ f, float4* __restrict__ fp, int total8) {
    int t = blockIdx.x * blockDim.x + threadIdx.x;
    if (t >= total8) return;
    int n = t >> 3, c = t & 7;
    float v[8];
    #pragma unroll
    for (int i = 0; i < 8; ++i) {
        int e = c * 8 + i;
        v[i] = (e < DF) ? f[n * DF + e] : 0.f;
    }
    float4 ov;
    __half2* op = (__half2*)&ov;
    #pragma unroll
    for (int i = 0; i < 4; ++i) op[i] = __floats2half2_rn(v[2 * i], v[2 * i + 1]);
    fp[t] = ov;
}

// One wave per TWO dst nodes. No shfl pipeline: each 8-lane group broadcast-loads
// its Edge directly; 4 edge loads + 4 row gathers in flight per 16-edge body.
__global__ __launch_bounds__(256) void hop_kernel(const _Float16* __restrict__ h,
    const Edge* __restrict__ ecw, const unsigned* __restrict__ rowStart,
    const unsigned* __restrict__ deg, const float* __restrict__ dinv,
    const float* __restrict__ selfw, _Float16* __restrict__ hn) {

    int lane = threadIdx.x & 63;
    int wid  = (int)((blockIdx.x * blockDim.x + threadIdx.x) >> 6);
    int half = lane >> 5;          // which node this lane serves
    int g    = (lane >> 3) & 3;    // edge sub-slot 0..3
    int qid  = lane & 7;           // 16B chunk within the 128B row

    int nd = 2 * wid + half;
    unsigned rs = rowStart[nd];
    unsigned d  = deg[nd];
    unsigned dmax = max(__shfl(d, 0), __shfl(d, 32));

    float acc[8] = {0.f, 0.f, 0.f, 0.f, 0.f, 0.f, 0.f, 0.f};

    for (unsigned j0 = 0; j0 < dmax; j0 += 16u) {
        #pragma unroll
        for (int u = 0; u < 4; ++u) {
            unsigned j = j0 + (unsigned)(g + 4 * u);
            bool valid = (j < d);
            unsigned idx = valid ? (rs + j) : 0u;   // ecw[0] always exists; w masked to 0
            Edge e = ecw[idx];                      // 8 lanes same addr -> broadcast
            float w = valid ? e.w : 0.f;
            half8 v = *(const half8*)(h + (long)e.c * DP + qid * 8);
            #pragma unroll
            for (int i = 0; i < 8; ++i) acc[i] += w * (float)v[i];   // v_fma_mix_f32
        }
    }

    // combine the 4 edge sub-slots within each half (lanes sharing qid)
    #pragma unroll
    for (int i = 0; i < 8; ++i) {
        acc[i] += __shfl_xor(acc[i], 8);
        acc[i] += __shfl_xor(acc[i], 16);
    }

    // row scale (dst factor) + self loop, pack to fp16
    float dw = dinv[nd];
    float sw = selfw[nd];
    half8 hv = *(const half8*)(h + (long)nd * DP + qid * 8);
    half8 ov;
    #pragma unroll
    for (int i = 0; i < 8; ++i)
        ov[i] = (_Float16)(dw * acc[i] + sw * (float)hv[i]);
    if ((lane & 24) == 0)
        *(half8*)(hn + (long)nd * DP + qid * 8) = ov;
}

// out[100000,47] = h2[100000,64(fp16)] @ Wp^T + b  via mfma_f32_16x16x32_f16.
// One wave per 16-row tile; 3 N-tiles x 2 K-blocks = 6 MFMA.
__global__ __launch_bounds__(256) void fc_kernel(const _Float16* __restrict__ h2,
    const float* __restrict__ W, const float* __restrict__ b,
    float* __restrict__ out, int MT) {

    __shared__ _Float16 sW[48 * 72];   // Wp[n][k], row stride 72 halves (bank-conflict pad)
    __shared__ float sB[48];

    for (int i = threadIdx.x; i < 48 * 64; i += 256) {
        int n = i >> 6, k = i & 63;
        float v = (n < NC && k < DF) ? W[n * DF + k] : 0.f;
        sW[n * 72 + k] = (_Float16)v;
    }
    if (threadIdx.x < 48) sB[threadIdx.x] = (threadIdx.x < NC) ? b[threadIdx.x] : 0.f;
    __syncthreads();

    int lane = threadIdx.x & 63;
    int wid  = (int)((blockIdx.x * blockDim.x + threadIdx.x) >> 6);
    if (wid >= MT) return;

    int m0 = wid * 16;
    int am = lane & 15;            // A row within tile / B col (n within tile)
    int aq = lane >> 4;            // k-quad: k = aq*8 + j

    const half8* arow = (const half8*)(h2 + (long)(m0 + am) * DP);
    half8 a0 = arow[aq];           // k = aq*8 .. +7
    half8 a1 = arow[aq + 4];       // k = 32 + aq*8 .. +7
    int row = aq * 4;

    #pragma unroll
    for (int t = 0; t < 3; ++t) {
        int n = t * 16 + am;
        const half8* brow = (const half8*)(sW + n * 72);
        half8 b0 = brow[aq];
        half8 b1 = brow[aq + 4];
        float4v c = {0.f, 0.f, 0.f, 0.f};
        c = __builtin_amdgcn_mfma_f32_16x16x32_f16(a0, b0, c, 0, 0, 0);
        c = __builtin_amdgcn_mfma_f32_16x16x32_f16(a1, b1, c, 0, 0, 0);
        if (n < NC) {
            float bn = sB[n];
            #pragma unroll
            for (int r = 0; r < 4; ++r)
                out[(long)(m0 + row + r) * NC + n] = c[r] + bn;
        }
    }
}

extern "C" void kernel_launch(void* const* d_in, const int* in_sizes, int n_in,
                              void* d_out, int out_size, void* d_ws, size_t ws_size,
                              hipStream_t stream) {
    const float* feat = (const float*)d_in[0];
    const float* W    = (const float*)d_in[1];
    const float* b    = (const float*)d_in[2];
    const int*  esrc  = (const int*)d_in[3];
    const int*  edst  = (const int*)d_in[4];
    float* out = (float*)d_out;

    char* ws = (char*)d_ws;
    unsigned* deg      = (unsigned*)ws; ws += NN * sizeof(unsigned);
    unsigned* total    = (unsigned*)ws; ws += 4 * sizeof(unsigned);   // memset with deg
    unsigned* cursor   = (unsigned*)ws; ws += NN * sizeof(unsigned);
    unsigned* rowStart = (unsigned*)ws; ws += NN * sizeof(unsigned);
    float*    dinv     = (float*)ws;    ws += NN * sizeof(float);
    float*    selfw    = (float*)ws;    ws += NN * sizeof(float);
    Edge*     ecw      = (Edge*)ws;     ws += (size_t)NE * sizeof(Edge);
    _Float16* featp    = (_Float16*)ws; ws += (size_t)NN * DP * sizeof(_Float16);
    _Float16* h1p      = (_Float16*)ws; ws += (size_t)NN * DP * sizeof(_Float16);
    _Float16* h2p      = (_Float16*)ws;

    hipMemsetAsync(deg, 0, (NN + 4) * sizeof(unsigned), stream);

    deg_kernel<<<(NE / 4 + 255) / 256, 256, 0, stream>>>((const int4*)edst, deg, NE / 4);
    alloc_kernel<<<(NN + 255) / 256, 256, 0, stream>>>(deg, dinv, selfw, rowStart, cursor, total, NN);
    fill_kernel<<<(NE / 8 + 255) / 256, 256, 0, stream>>>((const int4*)esrc, (const int4*)edst,
                                                          dinv, cursor, ecw, NE / 8);
    pad_kernel<<<(NN * 8 + 255) / 256, 256, 0, stream>>>(feat, (float4*)featp, NN * 8);

    const int hop_blocks = NN / 8;   // 2 nodes/wave, 4 waves/block, exact
    hop_kernel<<<hop_blocks, 256, 0, stream>>>(featp, ecw, rowStart, deg, dinv, selfw, h1p);
    hop_kernel<<<hop_blocks, 256, 0, stream>>>(h1p, ecw, rowStart, deg, dinv, selfw, h2p);

    const int MT = NN / 16;          // 6250 M-tiles
    fc_kernel<<<(MT + 3) / 4, 256, 0, stream>>>(h2p, W, b, out, MT);
}